// Round 1
// baseline (6968.018 us; speedup 1.0000x reference)
//
#include <hip/hip_runtime.h>
#include <math.h>

#define SEQ 200
#define KTOT 431   // 44 ptr + 128 enc + 1 closest + 2 pred + 256 hx

__device__ __forceinline__ float sigmoidf_(float x) { return 1.0f / (1.0f + __expf(-x)); }

// ---------------- W_out transpose: WoT[90][256] ----------------
__global__ void transpose_wout(const float* __restrict__ W_out, float* __restrict__ WoT) {
    int c = blockIdx.x;      // 0..89
    int k = threadIdx.x;     // 0..255
    WoT[c * 256 + k] = W_out[k * 90 + c];
}

// ---------------- Encoder + ptr transpose ----------------
// grid: SEQ*16 blocks (t, batch-chunk of 64), 256 threads
__global__ __launch_bounds__(256) void enc_kernel(
    const float* __restrict__ coords,
    const float* __restrict__ W_e1, const float* __restrict__ b_e1,
    const float* __restrict__ W_e2, const float* __restrict__ b_e2,
    float* __restrict__ enc_ws, float* __restrict__ ptr_ws)
{
    __shared__ float C[64][89];       // coords rows (pad 89 to spread banks)
    __shared__ float H[64][2][65];    // h_mean, padded
    __shared__ float W2[64][64];
    __shared__ float O[128][64];

    int t  = blockIdx.x >> 4;
    int bc = blockIdx.x & 15;
    int tid = threadIdx.x;

    for (int idx = tid; idx < 64 * 88; idx += 256) {
        int bl = idx / 88, j = idx - bl * 88;
        C[bl][j] = coords[((size_t)(bc * 64 + bl) * SEQ + t) * 88 + j];
    }
    for (int idx = tid; idx < 64 * 64; idx += 256)
        W2[idx >> 6][idx & 63] = W_e2[idx];
    __syncthreads();

    // phase A: per-team mean of relu(pts @ W_e1 + b_e1)
    {
        int b  = tid >> 2;
        int cq = (tid & 3) * 16;
        float w0[16], w1[16], bb[16];
#pragma unroll
        for (int c = 0; c < 16; c++) { w0[c] = W_e1[cq + c]; w1[c] = W_e1[64 + cq + c]; bb[c] = b_e1[cq + c]; }
        for (int tm = 0; tm < 2; tm++) {
            float acc[16];
#pragma unroll
            for (int c = 0; c < 16; c++) acc[c] = 0.f;
            for (int p = 0; p < 11; p++) {
                float x = C[b][(tm * 11 + p) * 4];
                float y = C[b][(tm * 11 + p) * 4 + 1];
#pragma unroll
                for (int c = 0; c < 16; c++) {
                    float h = fmaf(x, w0[c], fmaf(y, w1[c], bb[c]));
                    acc[c] += fmaxf(h, 0.f);
                }
            }
#pragma unroll
            for (int c = 0; c < 16; c++) H[b][tm][cq + c] = acc[c] * (1.0f / 11.0f);
        }
    }
    __syncthreads();

    // phase B: out = h_mean @ W_e2 + b_e2
    {
        int b  = tid >> 2;
        int tm = (tid >> 1) & 1;
        int ch = (tid & 1) * 32;
        float acc[32];
#pragma unroll
        for (int c = 0; c < 32; c++) acc[c] = 0.f;
        for (int k = 0; k < 64; k++) {
            float h = H[b][tm][k];
#pragma unroll
            for (int c = 0; c < 32; c++) acc[c] = fmaf(h, W2[k][ch + c], acc[c]);
        }
#pragma unroll
        for (int c = 0; c < 32; c++) O[tm * 64 + ch + c][b] = acc[c] + b_e2[ch + c];
    }
    __syncthreads();

    float* encT = enc_ws + (size_t)t * 128 * 1024 + bc * 64;
    for (int idx = tid; idx < 128 * 64; idx += 256) {
        int r = idx >> 6, b = idx & 63;
        encT[(size_t)r * 1024 + b] = O[r][b];
    }
    float* ptrT = ptr_ws + (size_t)t * 44 * 1024 + bc * 64;
    for (int idx = tid; idx < 44 * 64; idx += 256) {
        int j = idx >> 6, b = idx & 63;
        ptrT[(size_t)j * 1024 + b] = C[b][(j >> 1) * 4 + (j & 1)];
    }
}

// ---------------- Per-step kernel ----------------
// grid 256: bi = blockIdx.x&15 (64-batch tile), hj = blockIdx.x>>4 (16-hidden tile)
// t in [0, SEQ]: computes out_{t-1}+pred_{t-1} from hx_in, then (t<SEQ) gates+LSTM.
__global__ __launch_bounds__(256) void step_kernel(
    int t,
    const float* __restrict__ enc_ws, const float* __restrict__ ptr_ws,
    const float* __restrict__ hx_in, float* __restrict__ hx_out, float* __restrict__ cx,
    const float* __restrict__ W_ih, const float* __restrict__ b_ih,
    const float* __restrict__ W_hh, const float* __restrict__ b_hh,
    const float* __restrict__ WoT, const float* __restrict__ b_out,
    const float* __restrict__ pitch, float* __restrict__ d_out)
{
    __shared__ float X[KTOT][64];     // 110336 B
    __shared__ float U[2 * 4096];     // 32768 B: W chunk dbuf / P scratch / G gates
    __shared__ float Wo[8 * 256];     // 8192 B
    __shared__ float predL[64][2];    // 512 B

    int tid = threadIdx.x;
    int bi = blockIdx.x & 15, hj = blockIdx.x >> 4;
    int bg0 = bi * 64;

    // ---- stage X ----
    if (t < SEQ) {
        const float* ptrT = ptr_ws + (size_t)t * 44 * 1024 + bg0;
        for (int idx = tid; idx < 44 * 16; idx += 256) {
            int r = idx >> 4, q = idx & 15;
            *(float4*)&X[r][q * 4] = *(const float4*)(ptrT + (size_t)r * 1024 + q * 4);
        }
        const float* encT = enc_ws + (size_t)t * 128 * 1024 + bg0;
        for (int idx = tid; idx < 128 * 16; idx += 256) {
            int r = idx >> 4, q = idx & 15;
            *(float4*)&X[44 + r][q * 4] = *(const float4*)(encT + (size_t)r * 1024 + q * 4);
        }
    }
    {
        const float* hxT = hx_in + bg0;
        for (int idx = tid; idx < 256 * 16; idx += 256) {
            int r = idx >> 4, q = idx & 15;
            *(float4*)&X[175 + r][q * 4] = *(const float4*)(hxT + (size_t)r * 1024 + q * 4);
        }
    }
    // stage Wo: up to 8 W_out columns (6 out-slice + 2 pred)
    for (int idx = tid; idx < 8 * 256; idx += 256) {
        int c = idx >> 8, k = idx & 255;
        int col = (c < 6) ? (hj * 6 + c) : (88 + (c - 6));
        Wo[idx] = (col < 90) ? WoT[col * 256 + k] : 0.f;
    }
    __syncthreads();

    // ---- pred_{t-1} + out_{t-1} = hx_{t-1} @ W_out cols ----
    {
        int b = tid & 63, kq = tid >> 6;
        float accO[8];
#pragma unroll
        for (int c = 0; c < 8; c++) accO[c] = 0.f;
        if (t > 0) {
            for (int k = kq * 64; k < kq * 64 + 64; k++) {
                float xv = X[175 + k][b];
#pragma unroll
                for (int c = 0; c < 8; c++) accO[c] = fmaf(xv, Wo[c * 256 + k], accO[c]);
            }
        }
        float* P = U;  // [4][64][8]
#pragma unroll
        for (int c = 0; c < 8; c++) P[(kq * 64 + b) * 8 + c] = accO[c];
    }
    __syncthreads();
    if (tid < 128) {
        int b = tid >> 1, hf = tid & 1;
        const float* P = U;
#pragma unroll
        for (int j = 0; j < 4; j++) {
            int c = hf * 4 + j;
            float s = P[(0 * 64 + b) * 8 + c] + P[(1 * 64 + b) * 8 + c] +
                      P[(2 * 64 + b) * 8 + c] + P[(3 * 64 + b) * 8 + c];
            int col = (c < 6) ? (hj * 6 + c) : (88 + (c - 6));
            if (t > 0 && col < 90) {
                float v = (s + b_out[col]) * pitch[col & 1];
                if (c < 6) d_out[((size_t)(bg0 + b) * SEQ + (t - 1)) * 90 + col] = v;
                else predL[b][c - 6] = v;
            } else if (c >= 6) {
                predL[b][c - 6] = 0.f;
            }
        }
    }
    __syncthreads();

    if (t < SEQ) {
        // ---- closest distance; fill X rows 172..174 ----
        if (tid < 64) {
            int b = tid;
            float p0 = predL[b][0], p1 = predL[b][1];
            float m = 1e30f;
#pragma unroll
            for (int p = 0; p < 22; p++) {
                float dx = p0 - X[2 * p][b];
                float dy = p1 - X[2 * p + 1][b];
                m = fminf(m, fmaf(dx, dx, dy * dy));
            }
            X[172][b] = sqrtf(m);
            X[173][b] = p0;
            X[174][b] = p1;
        }
        __syncthreads();

        // ---- GEMM: gates[64b x 64c] over K=431, W chunks double-buffered ----
        int tb = tid & 15, tc = tid >> 4;
        float acc[4][4];
#pragma unroll
        for (int i = 0; i < 4; i++)
#pragma unroll
            for (int j = 0; j < 4; j++) acc[i][j] = 0.f;

        float4 pre[4];
        auto loadW = [&](int ch) {
#pragma unroll
            for (int i = 0; i < 4; i++) {
                int f4 = i * 256 + tid;
                int kr = f4 >> 4;
                int c4 = (f4 & 15) * 4;
                int k = ch * 64 + kr;
                int gcol = ((c4 >> 4) << 8) + hj * 16 + (c4 & 15);
                if (k < 175)      pre[i] = *(const float4*)&W_ih[(size_t)k * 1024 + gcol];
                else if (k < KTOT) pre[i] = *(const float4*)&W_hh[(size_t)(k - 175) * 1024 + gcol];
                else              pre[i] = make_float4(0.f, 0.f, 0.f, 0.f);
            }
        };
        auto storeW = [&](int buf) {
            float* Ub = U + buf * 4096;
#pragma unroll
            for (int i = 0; i < 4; i++) {
                int f4 = i * 256 + tid;
                int kr = f4 >> 4;
                int c4 = (f4 & 15) * 4;
                *(float4*)&Ub[kr * 64 + c4] = pre[i];
            }
        };
        loadW(0); storeW(0);
        __syncthreads();
        for (int ch = 0; ch < 7; ch++) {
            if (ch < 6) loadW(ch + 1);
            const float* Wc = U + (ch & 1) * 4096;
            const float* Xc = &X[ch * 64][0];
            int kend = (ch == 6) ? 47 : 64;
#pragma unroll 4
            for (int kr = 0; kr < kend; kr++) {
                float4 xv4 = *(const float4*)(Xc + kr * 64 + tb * 4);
                float4 wv4 = *(const float4*)(Wc + kr * 64 + tc * 4);
                float xv[4] = {xv4.x, xv4.y, xv4.z, xv4.w};
                float wv[4] = {wv4.x, wv4.y, wv4.z, wv4.w};
#pragma unroll
                for (int i = 0; i < 4; i++)
#pragma unroll
                    for (int j = 0; j < 4; j++)
                        acc[i][j] = fmaf(xv[i], wv[j], acc[i][j]);
            }
            if (ch < 6) storeW((ch & 1) ^ 1);
            __syncthreads();
        }

        // ---- exchange gates through LDS, LSTM pointwise ----
        float* G = U;  // [64 c_local][64 b]
#pragma unroll
        for (int i = 0; i < 4; i++)
#pragma unroll
            for (int j = 0; j < 4; j++)
                G[(tc * 4 + j) * 64 + (tb * 4 + i)] = acc[i][j];
        __syncthreads();
        {
            int b = tid & 63, hq = tid >> 6;
#pragma unroll
            for (int q = 0; q < 4; q++) {
                int hl = hq * 4 + q;              // 0..15
                int gb = hj * 16 + hl;            // global hidden index
                float iv = G[(0 + hl) * 64 + b] + b_ih[gb]       + b_hh[gb];
                float fv = G[(16 + hl) * 64 + b] + b_ih[256 + gb] + b_hh[256 + gb];
                float gv = G[(32 + hl) * 64 + b] + b_ih[512 + gb] + b_hh[512 + gb];
                float ov = G[(48 + hl) * 64 + b] + b_ih[768 + gb] + b_hh[768 + gb];
                size_t cidx = (size_t)gb * 1024 + bg0 + b;
                float c_old = cx[cidx];
                float c_new = fmaf(sigmoidf_(fv), c_old, sigmoidf_(iv) * tanhf(gv));
                cx[cidx] = c_new;
                hx_out[cidx] = sigmoidf_(ov) * tanhf(c_new);
            }
        }
    }
}

extern "C" void kernel_launch(void* const* d_in, const int* in_sizes, int n_in,
                              void* d_out, int out_size, void* d_ws, size_t ws_size,
                              hipStream_t stream) {
    const float* coords = (const float*)d_in[0];
    const float* pitch  = (const float*)d_in[1];
    const float* W_e1   = (const float*)d_in[2];
    const float* b_e1   = (const float*)d_in[3];
    const float* W_e2   = (const float*)d_in[4];
    const float* b_e2   = (const float*)d_in[5];
    const float* W_ih   = (const float*)d_in[6];
    const float* b_ih   = (const float*)d_in[7];
    const float* W_hh   = (const float*)d_in[8];
    const float* b_hh   = (const float*)d_in[9];
    const float* W_out  = (const float*)d_in[10];
    const float* b_out  = (const float*)d_in[11];
    float* out = (float*)d_out;
    float* ws  = (float*)d_ws;

    // ws layout (floats):
    float* hxA    = ws;                    // 262144
    float* cxb    = ws + 262144;           // 262144
    float* hxB    = ws + 524288;           // 262144
    float* WoT    = ws + 786432;           // 23040 (pad to 23040+...)
    float* ptr_ws = ws + 809472;           // 200*44*1024   = 9011200
    float* enc_ws = ws + 9820672;          // 200*128*1024  = 26214400
    // total 36,035,072 floats = ~137.5 MB

    // zero hxA + cx (poisoned 0xAA by harness)
    hipMemsetAsync(ws, 0, (size_t)2 * 262144 * sizeof(float), stream);

    transpose_wout<<<90, 256, 0, stream>>>(W_out, WoT);
    enc_kernel<<<SEQ * 16, 256, 0, stream>>>(coords, W_e1, b_e1, W_e2, b_e2, enc_ws, ptr_ws);

    for (int t = 0; t <= SEQ; t++) {
        const float* hin = (t & 1) ? hxB : hxA;
        float* hout      = (t & 1) ? hxA : hxB;
        step_kernel<<<256, 256, 0, stream>>>(t, enc_ws, ptr_ws, hin, hout, cxb,
                                             W_ih, b_ih, W_hh, b_hh, WoT, b_out, pitch, out);
    }
}